// Round 3
// baseline (69.800 us; speedup 1.0000x reference)
//
#include <hip/hip_runtime.h>

// BQWarp: ball query, N=32768 queries vs G=4096 db points, radius 0.25, K=10.
// Outputs (concatenated in d_out, float32):
//   [0, N*K)       mapping (first-K in-radius db indices in index order, 0 if invalid)
//   [N*K, N*K*4)   coords  (N,K,3) gathered db coords, 0 if invalid
//
// Round 3: wave-per-query ballot scan + float4-repacked db + prefetch.
//   - Prologue kernel repacks db (G,3) -> (Gpad,4) in d_ws, padding with 1e30
//     sentinels (never in radius) so the main loop has no bounds checks.
//   - Main loop: one global_load_dwordx4 per lane per chunk (vs 3 stride-12
//     dword loads: 18 -> 8 L2 cacheline transactions per wave-chunk).
//   - Prefetch chunk c+1 before processing chunk c to hide L2 latency.
//   - __ballot -> hit mask; slot = cnt + popc(mask below lane); per-wave
//     uniform early exit at cnt >= K.
//   - __f*_rn intrinsics pin the exact numpy rounding order (no FMA
//     contraction) so the d2 <= R^2 mask is bit-identical to the reference.

#define BQ_K 10
#define BQ_R2 0.0625f   // 0.25^2 exactly representable

__global__ __launch_bounds__(256) void bq_repack_kernel(
    const float* __restrict__ db, float4* __restrict__ db4, int G, int Gpad)
{
    const int i = blockIdx.x * 256 + threadIdx.x;
    if (i < Gpad) {
        if (i < G) {
            db4[i] = make_float4(db[3 * i + 0], db[3 * i + 1], db[3 * i + 2], 0.0f);
        } else {
            db4[i] = make_float4(1e30f, 1e30f, 1e30f, 0.0f);  // sentinel: never hits
        }
    }
}

__global__ __launch_bounds__(256) void bqwarp_kernel(
    const float* __restrict__ x,      // N*3 query coords
    const float4* __restrict__ db4,   // Gpad padded db
    float* __restrict__ out_map,      // N*K (indices as floats)
    float* __restrict__ out_pts,      // N*K*3
    int N, int nchunk)
{
    const int lane = threadIdx.x & 63;
    const int wave = threadIdx.x >> 6;
    const int q = blockIdx.x * 4 + wave;   // one query per wave
    if (q >= N) return;                    // wave-uniform

    const float qx = x[3 * q + 0];
    const float qy = x[3 * q + 1];
    const float qz = x[3 * q + 2];

    float* __restrict__ omap = out_map + (size_t)q * BQ_K;
    float* __restrict__ opts = out_pts + (size_t)q * BQ_K * 3;

    const unsigned long long below = (1ull << lane) - 1ull;

    int cnt = 0;                            // uniform across the wave
    float4 p = db4[lane];                   // chunk 0

    for (int c = 0; c < nchunk; ++c) {
        // Prefetch next chunk (last iteration re-fetches itself; harmless).
        const int cn = (c + 1 < nchunk) ? c + 1 : c;
        const float4 pn = db4[(cn << 6) | lane];

        // Exact numpy rounding order; no FMA contraction.
        const float dx = __fsub_rn(qx, p.x);
        const float dy = __fsub_rn(qy, p.y);
        const float dz = __fsub_rn(qz, p.z);
        const float d2 = __fadd_rn(
            __fadd_rn(__fmul_rn(dx, dx), __fmul_rn(dy, dy)),
            __fmul_rn(dz, dz));
        const bool hit = (d2 <= BQ_R2);     // sentinels give d2 = inf

        const unsigned long long m = __ballot(hit);
        if (hit) {
            const int slot = cnt + __popcll(m & below);
            if (slot < BQ_K) {
                const int gi = (c << 6) | lane;
                omap[slot] = (float)gi;
                opts[3 * slot + 0] = p.x;
                opts[3 * slot + 1] = p.y;
                opts[3 * slot + 2] = p.z;
            }
        }
        cnt += __popcll(m);
        if (cnt >= BQ_K) break;             // uniform
        p = pn;
    }

    // Zero-fill unused slots in parallel (d_out is poisoned before each launch).
    const int c0 = cnt < BQ_K ? cnt : BQ_K;
    if (lane >= c0 && lane < BQ_K) {
        omap[lane] = 0.0f;
        opts[3 * lane + 0] = 0.0f;
        opts[3 * lane + 1] = 0.0f;
        opts[3 * lane + 2] = 0.0f;
    }
}

extern "C" void kernel_launch(void* const* d_in, const int* in_sizes, int n_in,
                              void* d_out, int out_size, void* d_ws, size_t ws_size,
                              hipStream_t stream) {
    const float* x  = (const float*)d_in[0];   // (1, 32768, 3) float32
    const float* pg = (const float*)d_in[1];   // (1, 32, 16, 8, 3) float32

    const int N = in_sizes[0] / 3;   // 32768
    const int G = in_sizes[1] / 3;   // 4096

    float* out_map = (float*)d_out;                 // N*K floats
    float* out_pts = out_map + (size_t)N * BQ_K;    // N*K*3 floats

    const int nchunk = (G + 63) >> 6;
    const int Gpad = nchunk << 6;
    float4* db4 = (float4*)d_ws;                    // Gpad*16 bytes << ws_size

    bq_repack_kernel<<<(Gpad + 255) / 256, 256, 0, stream>>>(pg, db4, G, Gpad);

    const int block = 256;                          // 4 waves = 4 queries/block
    const int nblk = (N + 3) / 4;                   // 8192 blocks
    bqwarp_kernel<<<nblk, block, 0, stream>>>(x, db4, out_map, out_pts, N, nchunk);
}

// Round 4
// 68.099 us; speedup vs baseline: 1.0250x; 1.0250x over previous
//
#include <hip/hip_runtime.h>

// BQWarp: ball query, N=32768 queries vs G=4096 db points, radius 0.25, K=10.
// Outputs (concatenated in d_out, float32):
//   [0, N*K)       mapping (first-K in-radius db indices in index order, 0 if invalid)
//   [N*K, N*K*4)   coords  (N,K,3) gathered db coords, 0 if invalid
//
// Round 4: 4 queries per wave, shared chunk scan.
//   - 64 lanes load 64 consecutive db points (one chunk); the chunk is tested
//     against 4 query centers (independent ballot bodies -> ILP per load).
//   - waves: 8192 (= one full 8-waves/SIMD occupancy round on 1024 SIMDs);
//     total chunk-loads ~2.5x fewer than 1 query/wave.
//   - slot = cnt[j] + popc(ballot & below); first-K-in-index-order preserved.
//   - uniform early exit when all 4 queries have >= K hits.
//   - G = 4096 is a multiple of 64 -> no bounds checks, no padding, no d_ws.
//   - __f*_rn pins the exact numpy rounding order (no FMA contraction) so the
//     d2 <= R^2 mask is bit-identical to the reference.

#define BQ_K 10
#define BQ_R2 0.0625f   // 0.25^2 exactly representable
#define NQ 4            // queries per wave

__global__ __launch_bounds__(256, 8) void bqwarp_kernel(
    const float* __restrict__ x,      // N*3 query coords
    const float* __restrict__ db,     // G*3 db coords
    float* __restrict__ out_map,      // N*K (indices as floats)
    float* __restrict__ out_pts,      // N*K*3
    int N, int G)
{
    const int lane = threadIdx.x & 63;
    const int wave = threadIdx.x >> 6;
    const int qb = (blockIdx.x * 4 + wave) * NQ;   // base query for this wave
    if (qb >= N) return;                           // wave-uniform

    float qx[NQ], qy[NQ], qz[NQ];
    int cnt[NQ];
#pragma unroll
    for (int j = 0; j < NQ; ++j) {
        qx[j] = x[3 * (qb + j) + 0];
        qy[j] = x[3 * (qb + j) + 1];
        qz[j] = x[3 * (qb + j) + 2];
        cnt[j] = 0;
    }

    const unsigned long long below = (1ull << lane) - 1ull;
    const int nchunk = G >> 6;                     // 64

    // chunk 0
    float px = db[3 * lane + 0];
    float py = db[3 * lane + 1];
    float pz = db[3 * lane + 2];

    for (int c = 0; c < nchunk; ++c) {
        // Prefetch next chunk (last iteration re-fetches itself; harmless).
        const int cn = (c + 1 < nchunk) ? c + 1 : c;
        const int gn = (cn << 6) | lane;
        const float nx = db[3 * gn + 0];
        const float ny = db[3 * gn + 1];
        const float nz = db[3 * gn + 2];

        const int gi = (c << 6) | lane;

#pragma unroll
        for (int j = 0; j < NQ; ++j) {
            // Exact numpy rounding order; no FMA contraction.
            const float dx = __fsub_rn(qx[j], px);
            const float dy = __fsub_rn(qy[j], py);
            const float dz = __fsub_rn(qz[j], pz);
            const float d2 = __fadd_rn(
                __fadd_rn(__fmul_rn(dx, dx), __fmul_rn(dy, dy)),
                __fmul_rn(dz, dz));
            const bool hit = (d2 <= BQ_R2);
            const unsigned long long m = __ballot(hit);
            if (hit) {
                const int slot = cnt[j] + __popcll(m & below);
                if (slot < BQ_K) {
                    float* omap = out_map + (size_t)(qb + j) * BQ_K;
                    float* opts = out_pts + (size_t)(qb + j) * BQ_K * 3;
                    omap[slot] = (float)gi;
                    opts[3 * slot + 0] = px;
                    opts[3 * slot + 1] = py;
                    opts[3 * slot + 2] = pz;
                }
            }
            cnt[j] += __popcll(m);
        }

        if (cnt[0] >= BQ_K && cnt[1] >= BQ_K &&
            cnt[2] >= BQ_K && cnt[3] >= BQ_K) break;   // uniform

        px = nx; py = ny; pz = nz;
    }

    // Parallel zero-fill of unused slots (d_out is poisoned before each launch).
    // Lanes [16j, 16j+K) own query j's tail.
#pragma unroll
    for (int j = 0; j < NQ; ++j) {
        const int s = lane - 16 * j;
        const int c0 = cnt[j] < BQ_K ? cnt[j] : BQ_K;
        if (s >= c0 && s < BQ_K) {
            float* omap = out_map + (size_t)(qb + j) * BQ_K;
            float* opts = out_pts + (size_t)(qb + j) * BQ_K * 3;
            omap[s] = 0.0f;
            opts[3 * s + 0] = 0.0f;
            opts[3 * s + 1] = 0.0f;
            opts[3 * s + 2] = 0.0f;
        }
    }
}

extern "C" void kernel_launch(void* const* d_in, const int* in_sizes, int n_in,
                              void* d_out, int out_size, void* d_ws, size_t ws_size,
                              hipStream_t stream) {
    const float* x  = (const float*)d_in[0];   // (1, 32768, 3) float32
    const float* pg = (const float*)d_in[1];   // (1, 32, 16, 8, 3) float32

    const int N = in_sizes[0] / 3;   // 32768
    const int G = in_sizes[1] / 3;   // 4096

    float* out_map = (float*)d_out;                 // N*K floats
    float* out_pts = out_map + (size_t)N * BQ_K;    // N*K*3 floats

    const int block = 256;                          // 4 waves x 4 queries = 16 queries/block
    const int nblk = (N + 16 - 1) / 16;             // 2048 blocks
    bqwarp_kernel<<<nblk, block, 0, stream>>>(x, pg, out_map, out_pts, N, G);
}